// Round 8
// baseline (371.068 us; speedup 1.0000x reference)
//
#include <hip/hip_runtime.h>
#include <hip/hip_bf16.h>
#include <math.h>

// Problem constants
#define B_   32
#define N_   2248
#define C_   1024
#define D_   128
#define P_   200
#define T_   2048            // N_ - P_
#define M_   (B_ * N_)       // 71936 rows total
#define SCALE_ 0.08838834764831845f  // D^-0.5

typedef __bf16 bf16;
typedef __bf16 bf16x8 __attribute__((ext_vector_type(8)));
typedef __bf16 bf16x4 __attribute__((ext_vector_type(4)));
typedef float  f32x4  __attribute__((ext_vector_type(4)));
typedef unsigned int u32x4 __attribute__((ext_vector_type(4)));

// V-transpose LDS column swizzle (attn): keeps 8-contiguous t within a 16B
// block, XORs the 8-block index with (d>>3)&7 to spread banks.
#define VT_COL(dd, t) ((((((t) >> 3) ^ (((dd) >> 3) & 7)) << 3)) | ((t) & 7))

// ---------------------------------------------------------------------------
// Kernel 0: one-time weight transpose + bf16 convert.
// WtD[d][k] = W_down[k][d] (d<128, k<1024);  WtU[c][d] = W_up[d][c]
// ---------------------------------------------------------------------------
__global__ void k_prep(const float* __restrict__ Wd, const float* __restrict__ Wu,
                       bf16* __restrict__ WtD, bf16* __restrict__ WtU) {
    int i = blockIdx.x * 256 + threadIdx.x;
    if (i >= 131072) return;
    int d = i >> 10, k = i & 1023;
    WtD[i] = (bf16)Wd[k * 128 + d];
    int c = i >> 7, e = i & 127;
    WtU[i] = (bf16)Wu[e * 1024 + c];
}

// ---------------------------------------------------------------------------
// Kernel A: down = gelu(x @ W_down + b_down), bf16 out.
// r3's reg->LDS double-buffer structure (the compiler-proof prefetch: the
// LDS write before the barrier FORCES the loads to stay hoisted), re-shaped
// for 16 waves/CU: 64-row x 128-col tile, BK=128 (8 k-steps).
//   per step: barrier; issue NEXT tile's 8 independent f32x4 loads;
//   compute current tile from LDS (B frags direct from L2-resident WtD);
//   convert+write regs -> alternate LDS buffer.
// acc[8]=32 VGPR, stg[8]=32 VGPR, LDS 34.8 KB -> launch_bounds(256,4):
// 4 blocks/CU = 16 waves/CU, in-flight 128 KB/CU (4/3 x r3's 96 KB).
// grid = 1124. Wave w owns rows w*16..+15, all 128 output cols.
// ---------------------------------------------------------------------------
__launch_bounds__(256, 4)
__global__ void k_down(const float* __restrict__ x, const bf16* __restrict__ WtD,
                       const float* __restrict__ bd, bf16* __restrict__ down) {
    __shared__ bf16 As[2][64][136];   // dbuf, +8 pad (272B row stride)
    const int tid = threadIdx.x;
    const int lane = tid & 63, w = tid >> 6;
    const int li = lane & 15, lg = lane >> 4;
    const int m0 = blockIdx.x * 64;
    const bf16* Bp = WtD + (size_t)li * C_ + lg * 8;

    // staging coords: 1024 chunks of 8 floats (64 rows x 128 k), 4/thread
    int r_[4], c_[4];
    const float* sp[4];
#pragma unroll
    for (int it = 0; it < 4; it++) {
        int ch = tid + it * 256;        // 0..1023
        r_[it] = ch >> 4;               // 0..63
        c_[it] = (ch & 15) * 8;         // 0..120
        sp[it] = x + (size_t)(m0 + r_[it]) * C_ + c_[it];
    }

    f32x4 stg[8];
    // prologue: load k-tile 0, write buffer 0
#pragma unroll
    for (int it = 0; it < 4; it++) {
        stg[2 * it]     = *(const f32x4*)(sp[it]);
        stg[2 * it + 1] = *(const f32x4*)(sp[it] + 4);
    }
#pragma unroll
    for (int it = 0; it < 4; it++) {
        bf16x8 o;
        o[0] = (bf16)stg[2*it][0];   o[1] = (bf16)stg[2*it][1];
        o[2] = (bf16)stg[2*it][2];   o[3] = (bf16)stg[2*it][3];
        o[4] = (bf16)stg[2*it+1][0]; o[5] = (bf16)stg[2*it+1][1];
        o[6] = (bf16)stg[2*it+1][2]; o[7] = (bf16)stg[2*it+1][3];
        *(bf16x8*)&As[0][r_[it]][c_[it]] = o;
    }

    f32x4 acc[8];
    const f32x4 zero = {0.f, 0.f, 0.f, 0.f};
#pragma unroll
    for (int f = 0; f < 8; f++) acc[f] = zero;

    int cur = 0;
    for (int t = 0; t < 8; t++) {
        __syncthreads();                    // buf[cur] fully written
        if (t < 7) {
            // issue next tile's loads NOW; they complete under the MFMAs
#pragma unroll
            for (int it = 0; it < 4; it++) {
                stg[2 * it]     = *(const f32x4*)(sp[it] + (t + 1) * 128);
                stg[2 * it + 1] = *(const f32x4*)(sp[it] + (t + 1) * 128 + 4);
            }
        }
        const int k0 = t * 128;
#pragma unroll
        for (int kk = 0; kk < 4; kk++) {
            bf16x8 af = *(const bf16x8*)&As[cur][w * 16 + li][kk * 32 + lg * 8];
#pragma unroll
            for (int f = 0; f < 8; f++) {
                bf16x8 bf_ = *(const bf16x8*)(Bp + (size_t)(f * 16) * C_ + k0 + kk * 32);
                acc[f] = __builtin_amdgcn_mfma_f32_16x16x32_bf16(af, bf_, acc[f], 0, 0, 0);
            }
        }
        if (t < 7) {
            // convert + write the buffer nobody reads until next barrier
#pragma unroll
            for (int it = 0; it < 4; it++) {
                bf16x8 o;
                o[0] = (bf16)stg[2*it][0];   o[1] = (bf16)stg[2*it][1];
                o[2] = (bf16)stg[2*it][2];   o[3] = (bf16)stg[2*it][3];
                o[4] = (bf16)stg[2*it+1][0]; o[5] = (bf16)stg[2*it+1][1];
                o[6] = (bf16)stg[2*it+1][2]; o[7] = (bf16)stg[2*it+1][3];
                *(bf16x8*)&As[cur ^ 1][r_[it]][c_[it]] = o;
            }
        }
        cur ^= 1;
    }
    // epilogue: bias + exact gelu, store bf16
#pragma unroll
    for (int f = 0; f < 8; f++) {
        int col = f * 16 + li;
        float bias = bd[col];
#pragma unroll
        for (int r = 0; r < 4; r++) {
            float v = acc[f][r] + bias;
            float g = 0.5f * v * (1.0f + erff(v * 0.70710678118654752f));
            down[(size_t)(m0 + w * 16 + lg * 4 + r) * D_ + col] = (bf16)g;
        }
    }
}

// ---------------------------------------------------------------------------
// Kernel B: flash attention, SPLIT over tokens (4 quarters of 512).
// grid = 32 b x 4 qtile x 4 thalf = 512 blocks (2/CU), XCD-swizzled.
// 4 waves; wave w owns q rows w*16..w*16+15. Token tiles of 64.
// Writes unnormalized partial O + running (m, l) per q row.
// ---------------------------------------------------------------------------
__launch_bounds__(256, 2)
__global__ void k_attn(const bf16* __restrict__ down, float* __restrict__ Opart,
                       float* __restrict__ Mpart, float* __restrict__ Lpart) {
    __shared__ bf16 Qs[64][136];
    __shared__ bf16 Ks[64][136];      // token tile row-major [t][d]
    __shared__ bf16 Vt[128][72];      // transposed [d][t], VT_COL swizzled
    __shared__ bf16 Ps[4][16][72];    // per-wave P tile [q][t]
    const int tid = threadIdx.x;
    const int lane = tid & 63, w = tid >> 6;
    const int li = lane & 15, lg = lane >> 4;
    // bijective XCD swizzle (512 % 8 == 0): XCD x gets 64 contiguous wgs
    const int bid = blockIdx.x;
    const int wg = (bid & 7) * 64 + (bid >> 3);
    const int b  = wg >> 4;
    const int qt = (wg >> 2) & 3;
    const int th = wg & 3;
    const size_t base = (size_t)b * N_ * D_;
    const int tbase = P_ + th * 512;

    // stage Q (rows qt*64 .. +63)
#pragma unroll
    for (int it = 0; it < 4; it++) {
        int ch = tid + it * 256;            // 1024 chunks of 8
        int r = ch >> 4, c8 = (ch & 15) * 8;
        *(u32x4*)&Qs[r][c8] = *(const u32x4*)(down + base + (size_t)(qt * 64 + r) * D_ + c8);
    }
    __syncthreads();
    bf16x8 qf[4];
#pragma unroll
    for (int kk = 0; kk < 4; kk++)
        qf[kk] = *(const bf16x8*)&Qs[w * 16 + li][kk * 32 + lg * 8];

    float m_run[4], l_run[4];
    f32x4 acc[8];
    const f32x4 zero = {0.f, 0.f, 0.f, 0.f};
#pragma unroll
    for (int r = 0; r < 4; r++) { m_run[r] = -3.0e38f; l_run[r] = 0.f; }
#pragma unroll
    for (int fn = 0; fn < 8; fn++) acc[fn] = zero;

    for (int tt = 0; tt < 8; tt++) {
        __syncthreads();
        // stage token tile: row-major K copy + swizzled transposed V copy
#pragma unroll
        for (int it = 0; it < 4; it++) {
            int ch = tid + it * 256;
            int r = ch >> 4, c8 = (ch & 15) * 8;
            u32x4 v = *(const u32x4*)(down + base + (size_t)(tbase + tt * 64 + r) * D_ + c8);
            *(u32x4*)&Ks[r][c8] = v;
            bf16 tmp[8];
            *(u32x4*)tmp = v;
#pragma unroll
            for (int j = 0; j < 8; j++) Vt[c8 + j][VT_COL(c8 + j, r)] = tmp[j];
        }
        __syncthreads();
        // S = Q K^T * scale   (wave: 16 q x 64 t)
        f32x4 s[4];
#pragma unroll
        for (int fn = 0; fn < 4; fn++) {
            s[fn] = zero;
#pragma unroll
            for (int kk = 0; kk < 4; kk++) {
                bf16x8 kf = *(const bf16x8*)&Ks[fn * 16 + li][kk * 32 + lg * 8];
                s[fn] = __builtin_amdgcn_mfma_f32_16x16x32_bf16(qf[kk], kf, s[fn], 0, 0, 0);
            }
            s[fn] *= SCALE_;
        }
        // online softmax (rows shared by 16-lane group; reduce over li)
#pragma unroll
        for (int r = 0; r < 4; r++) {
            float tmax = fmaxf(fmaxf(s[0][r], s[1][r]), fmaxf(s[2][r], s[3][r]));
#pragma unroll
            for (int off = 1; off < 16; off <<= 1)
                tmax = fmaxf(tmax, __shfl_xor(tmax, off, 64));
            float mnew = fmaxf(m_run[r], tmax);
            float corr = __expf(m_run[r] - mnew);
            m_run[r] = mnew;
            float psum = 0.f;
#pragma unroll
            for (int fn = 0; fn < 4; fn++) {
                float p = __expf(s[fn][r] - mnew);
                psum += p;
                Ps[w][lg * 4 + r][fn * 16 + li] = (bf16)p;
            }
#pragma unroll
            for (int off = 1; off < 16; off <<= 1)
                psum += __shfl_xor(psum, off, 64);
            l_run[r] = l_run[r] * corr + psum;
#pragma unroll
            for (int fn = 0; fn < 8; fn++) acc[fn][r] *= corr;
        }
        // O += P V   (P: 16x64 per wave, V: 64x128)
#pragma unroll
        for (int kk = 0; kk < 2; kk++) {
            bf16x8 pf = *(const bf16x8*)&Ps[w][li][kk * 32 + lg * 8];
#pragma unroll
            for (int fn = 0; fn < 8; fn++) {
                int d = fn * 16 + li;
                bf16x8 vf = *(const bf16x8*)&Vt[d][VT_COL(d, kk * 32 + lg * 8)];
                acc[fn] = __builtin_amdgcn_mfma_f32_16x16x32_bf16(pf, vf, acc[fn], 0, 0, 0);
            }
        }
    }
    // epilogue: store unnormalized partials + (m, l) for all 64 q rows
#pragma unroll
    for (int r = 0; r < 4; r++) {
        int q = qt * 64 + w * 16 + lg * 4 + r;
        size_t ro = ((size_t)(b * 4 + th) * 256 + q) * 128;
#pragma unroll
        for (int fn = 0; fn < 8; fn++)
            Opart[ro + fn * 16 + li] = acc[fn][r];
        if (li == 0) {
            Mpart[(b * 4 + th) * 256 + q] = m_run[r];
            Lpart[(b * 4 + th) * 256 + q] = l_run[r];
        }
    }
}

// ---------------------------------------------------------------------------
// Kernel B2: combine the four token-quarter partials into pout (bf16).
// 819200 elems / 4 per thread = 204800 threads = 800 blocks x 256.
// ---------------------------------------------------------------------------
__global__ void k_comb(const float* __restrict__ Opart, const float* __restrict__ Mpart,
                       const float* __restrict__ Lpart, bf16* __restrict__ pout) {
    int gid = blockIdx.x * 256 + threadIdx.x;
    if (gid >= (B_ * P_ * D_) / 4) return;
    int e = gid * 4;
    int row = e >> 7;                 // 0..6399  (b*200+q)
    int col = e & 127;
    int b = row / P_;
    int q = row - b * P_;
    float mm[4], ll[4];
    float m = -3.0e38f;
#pragma unroll
    for (int t = 0; t < 4; t++) {
        mm[t] = Mpart[(b * 4 + t) * 256 + q];
        ll[t] = Lpart[(b * 4 + t) * 256 + q];
        m = fmaxf(m, mm[t]);
    }
    float a[4], lsum = 0.f;
#pragma unroll
    for (int t = 0; t < 4; t++) { a[t] = __expf(mm[t] - m); lsum += ll[t] * a[t]; }
    float inv = 1.0f / lsum;
    f32x4 o = {0.f, 0.f, 0.f, 0.f};
#pragma unroll
    for (int t = 0; t < 4; t++) {
        f32x4 ot = *(const f32x4*)&Opart[((size_t)(b * 4 + t) * 256 + q) * 128 + col];
#pragma unroll
        for (int j = 0; j < 4; j++) o[j] += ot[j] * a[t];
    }
    bf16x4 ob;
#pragma unroll
    for (int j = 0; j < 4; j++) ob[j] = (bf16)(o[j] * inv);
    *(bf16x4*)&pout[(size_t)row * 128 + col] = ob;
}

// ---------------------------------------------------------------------------
// Kernel C: out = gate * (combined @ W_up + b_up).  K=128 single shot.
// DIRECT-FRAGMENT GEMM: no LDS, no barriers. All loads issue up front
// (single K block -> no dependent per-iteration chain).
// 128x128 tile, 4 waves (2x2). XCD-aware block swizzle (4496 % 8 == 0).
// ---------------------------------------------------------------------------
__launch_bounds__(256, 3)
__global__ void k_up(const bf16* __restrict__ down, const bf16* __restrict__ pout,
                     const bf16* __restrict__ WtU, const float* __restrict__ bu,
                     const float* __restrict__ gate, float* __restrict__ out) {
    const int tid = threadIdx.x;
    const int lane = tid & 63, wid = tid >> 6;
    const int wm = wid >> 1, wn = wid & 1;
    const int li = lane & 15, lg = lane >> 4;
    // bijective XCD swizzle: XCD x gets contiguous wg range [562x, 562x+562)
    int bid = blockIdx.x;
    int wg = (bid & 7) * 562 + (bid >> 3);
    const int mt = wg >> 3, nt = wg & 7;
    const int m0 = mt * 128, n0 = nt * 128;

    // per-lane A row pointers (combined matrix), one per fm fragment
    const bf16* rp[4];
#pragma unroll
    for (int f = 0; f < 4; f++) {
        int row = m0 + wm * 64 + f * 16 + li;
        int bb = row / N_;
        int n = row - bb * N_;
        rp[f] = (n < P_) ? (pout + (size_t)(bb * P_ + n) * D_ + lg * 8)
                         : (down + (size_t)row * D_ + lg * 8);
    }
    const bf16* Bp = WtU + (size_t)(n0 + wn * 64 + li) * D_ + lg * 8;

    f32x4 acc[4][4];
    const f32x4 zero = {0.f, 0.f, 0.f, 0.f};
#pragma unroll
    for (int i = 0; i < 4; i++)
#pragma unroll
        for (int j = 0; j < 4; j++) acc[i][j] = zero;

#pragma unroll
    for (int kk = 0; kk < 4; kk++) {
        bf16x8 af[4], bf_[4];
#pragma unroll
        for (int f = 0; f < 4; f++) {
            af[f]  = *(const bf16x8*)(rp[f] + kk * 32);
            bf_[f] = *(const bf16x8*)(Bp + (size_t)(f * 16) * D_ + kk * 32);
        }
#pragma unroll
        for (int fm = 0; fm < 4; fm++)
#pragma unroll
            for (int fn = 0; fn < 4; fn++)
                acc[fm][fn] = __builtin_amdgcn_mfma_f32_16x16x32_bf16(
                    af[fm], bf_[fn], acc[fm][fn], 0, 0, 0);
    }

    float g = gate[0];
#pragma unroll
    for (int fn = 0; fn < 4; fn++) {
        int c = n0 + wn * 64 + fn * 16 + li;
        float bias = bu[c];
#pragma unroll
        for (int fm = 0; fm < 4; fm++) {
            int rb = m0 + wm * 64 + fm * 16 + lg * 4;
#pragma unroll
            for (int r = 0; r < 4; r++)
                out[(size_t)(rb + r) * C_ + c] = g * (acc[fm][fn][r] + bias);
        }
    }
}

// ---------------------------------------------------------------------------
extern "C" void kernel_launch(void* const* d_in, const int* in_sizes, int n_in,
                              void* d_out, int out_size, void* d_ws, size_t ws_size,
                              hipStream_t stream) {
    const float* x    = (const float*)d_in[0];
    const float* Wd   = (const float*)d_in[1];
    const float* bd   = (const float*)d_in[2];
    const float* Wu   = (const float*)d_in[3];
    const float* bu   = (const float*)d_in[4];
    const float* gate = (const float*)d_in[5];
    float* out = (float*)d_out;

    char* w = (char*)d_ws;
    bf16*  down  = (bf16*)w;                          // 71936*128*2 = 18,415,616 B
    bf16*  pout  = (bf16*)(w + 18415616);             // 32*200*128*2 = 1,638,400 B
    bf16*  WtD   = (bf16*)(w + 20054016);             // 262,144 B
    bf16*  WtU   = (bf16*)(w + 20316160);             // 262,144 B
    float* Opart = (float*)(w + 20578304);            // 32*4*256*128*4 = 16,777,216 B
    float* Mpart = (float*)(w + 37355520);            // 131,072 B
    float* Lpart = (float*)(w + 37486592);            // 131,072 B  (total 37.6 MB)

    k_prep<<<512, 256, 0, stream>>>(Wd, Wu, WtD, WtU);
    k_down<<<M_ / 64, 256, 0, stream>>>(x, WtD, bd, down);             // 1124 blocks
    k_attn<<<512, 256, 0, stream>>>(down, Opart, Mpart, Lpart);        // 512 blocks
    k_comb<<<800, 256, 0, stream>>>(Opart, Mpart, Lpart, pout);        // 800 blocks
    k_up<<<(M_ / 128) * 8, 256, 0, stream>>>(down, pout, WtU, bu, gate, out); // 4496
}

// Round 9
// 266.009 us; speedup vs baseline: 1.3949x; 1.3949x over previous
//
#include <hip/hip_runtime.h>
#include <hip/hip_bf16.h>
#include <math.h>

// Problem constants
#define B_   32
#define N_   2248
#define C_   1024
#define D_   128
#define P_   200
#define T_   2048            // N_ - P_
#define M_   (B_ * N_)       // 71936 rows total
#define SCALE_ 0.08838834764831845f  // D^-0.5

typedef __bf16 bf16;
typedef __bf16 bf16x8 __attribute__((ext_vector_type(8)));
typedef __bf16 bf16x4 __attribute__((ext_vector_type(4)));
typedef float  f32x4  __attribute__((ext_vector_type(4)));
typedef unsigned int u32x4 __attribute__((ext_vector_type(4)));

// V-transpose LDS column swizzle (attn): keeps 8-contiguous t within a 16B
// block, XORs the 8-block index with (d>>3)&7 to spread banks.
#define VT_COL(dd, t) ((((((t) >> 3) ^ (((dd) >> 3) & 7)) << 3)) | ((t) & 7))

// ---------------------------------------------------------------------------
// Kernel 0: one-time weight transpose + bf16 convert.
// WtD[d][k] = W_down[k][d] (d<128, k<1024);  WtU[c][d] = W_up[d][c]
// ---------------------------------------------------------------------------
__global__ void k_prep(const float* __restrict__ Wd, const float* __restrict__ Wu,
                       bf16* __restrict__ WtD, bf16* __restrict__ WtU) {
    int i = blockIdx.x * 256 + threadIdx.x;
    if (i >= 131072) return;
    int d = i >> 10, k = i & 1023;
    WtD[i] = (bf16)Wd[k * 128 + d];
    int c = i >> 7, e = i & 127;
    WtU[i] = (bf16)Wu[e * 1024 + c];
}

// ---------------------------------------------------------------------------
// Kernel A: down = gelu(x @ W_down + b_down), bf16 out.
// EXACT round-3 structure (best measured: ~149 us) + sched_barrier(0) pins.
// The pins stop hipcc from sinking the staging loads past the MFMA cluster
// (r7/r8 post-mortem: VGPR 52/60 = loads sunk = 0.6 TB/s). With the pin,
// the 8 f32x4 loads issue BEFORE the MFMAs and stay in flight under them:
// 12 waves/CU x 8 KB = 96 KB/CU in flight.
// 128x128 tile, BK=64, 4 waves (2x2), reg->LDS double-buffer.
// ---------------------------------------------------------------------------
__launch_bounds__(256, 3)
__global__ void k_down(const float* __restrict__ x, const bf16* __restrict__ WtD,
                       const float* __restrict__ bd, bf16* __restrict__ down) {
    __shared__ bf16 As[2][128][72];   // double-buffered x tile (144B stride)
    const int tid = threadIdx.x;
    const int lane = tid & 63, wid = tid >> 6;
    const int wm = wid >> 1, wn = wid & 1;
    const int li = lane & 15, lg = lane >> 4;
    const int m0 = blockIdx.x * 128;
    const bf16* Bp = WtD + (size_t)(wn * 64 + li) * C_ + lg * 8;

    // per-thread staging coordinates: 4 chunks of 8 floats (1024 chunks total)
    int r_[4], c_[4];
    const float* sp[4];
#pragma unroll
    for (int it = 0; it < 4; it++) {
        int ch = tid + it * 256;
        r_[it] = ch >> 3;
        c_[it] = (ch & 7) * 8;
        sp[it] = x + (size_t)(m0 + r_[it]) * C_ + c_[it];
    }

    f32x4 stg[8];
    // prologue: load k-tile 0 and write buffer 0
#pragma unroll
    for (int it = 0; it < 4; it++) {
        stg[2 * it]     = *(const f32x4*)(sp[it]);
        stg[2 * it + 1] = *(const f32x4*)(sp[it] + 4);
    }
#pragma unroll
    for (int it = 0; it < 4; it++) {
        bf16x8 o;
        o[0] = (bf16)stg[2*it][0]; o[1] = (bf16)stg[2*it][1];
        o[2] = (bf16)stg[2*it][2]; o[3] = (bf16)stg[2*it][3];
        o[4] = (bf16)stg[2*it+1][0]; o[5] = (bf16)stg[2*it+1][1];
        o[6] = (bf16)stg[2*it+1][2]; o[7] = (bf16)stg[2*it+1][3];
        *(bf16x8*)&As[0][r_[it]][c_[it]] = o;
    }

    f32x4 acc[4][4];
    const f32x4 zero = {0.f, 0.f, 0.f, 0.f};
#pragma unroll
    for (int i = 0; i < 4; i++)
#pragma unroll
        for (int j = 0; j < 4; j++) acc[i][j] = zero;

    int cur = 0;
    for (int t = 0; t < 16; t++) {
        __syncthreads();                    // buf[cur] fully written
        if (t < 15) {
            // issue next tile's loads NOW; the pin below keeps them here
#pragma unroll
            for (int it = 0; it < 4; it++) {
                stg[2 * it]     = *(const f32x4*)(sp[it] + (t + 1) * 64);
                stg[2 * it + 1] = *(const f32x4*)(sp[it] + (t + 1) * 64 + 4);
            }
        }
        __builtin_amdgcn_sched_barrier(0);  // loads stay ABOVE the MFMAs
        const int k0 = t * 64;
#pragma unroll
        for (int kk = 0; kk < 2; kk++) {
            bf16x8 af[4], bf_[4];
#pragma unroll
            for (int f = 0; f < 4; f++)
                bf_[f] = *(const bf16x8*)(Bp + (size_t)(f * 16) * C_ + k0 + kk * 32);
#pragma unroll
            for (int f = 0; f < 4; f++)
                af[f] = *(const bf16x8*)&As[cur][wm * 64 + f * 16 + li][kk * 32 + lg * 8];
#pragma unroll
            for (int fm = 0; fm < 4; fm++)
#pragma unroll
                for (int fn = 0; fn < 4; fn++)
                    acc[fm][fn] = __builtin_amdgcn_mfma_f32_16x16x32_bf16(
                        af[fm], bf_[fn], acc[fm][fn], 0, 0, 0);
        }
        __builtin_amdgcn_sched_barrier(0);  // converts/writes stay BELOW
        if (t < 15) {
            // convert + write into the buffer nobody reads until next barrier
#pragma unroll
            for (int it = 0; it < 4; it++) {
                bf16x8 o;
                o[0] = (bf16)stg[2*it][0]; o[1] = (bf16)stg[2*it][1];
                o[2] = (bf16)stg[2*it][2]; o[3] = (bf16)stg[2*it][3];
                o[4] = (bf16)stg[2*it+1][0]; o[5] = (bf16)stg[2*it+1][1];
                o[6] = (bf16)stg[2*it+1][2]; o[7] = (bf16)stg[2*it+1][3];
                *(bf16x8*)&As[cur ^ 1][r_[it]][c_[it]] = o;
            }
        }
        cur ^= 1;
    }
    // epilogue: bias + exact gelu, store bf16
#pragma unroll
    for (int fn = 0; fn < 4; fn++) {
        int col = wn * 64 + fn * 16 + li;
        float bias = bd[col];
#pragma unroll
        for (int fm = 0; fm < 4; fm++) {
            int rb = m0 + wm * 64 + fm * 16 + lg * 4;
#pragma unroll
            for (int r = 0; r < 4; r++) {
                float v = acc[fm][fn][r] + bias;
                float g = 0.5f * v * (1.0f + erff(v * 0.70710678118654752f));
                down[(size_t)(rb + r) * D_ + col] = (bf16)g;
            }
        }
    }
}

// ---------------------------------------------------------------------------
// Kernel B: flash attention, SPLIT over tokens (4 quarters of 512).
// grid = 32 b x 4 qtile x 4 thalf = 512 blocks (2/CU), XCD-swizzled.
// 4 waves; wave w owns q rows w*16..w*16+15. Token tiles of 64.
// Writes unnormalized partial O + running (m, l) per q row.
// ---------------------------------------------------------------------------
__launch_bounds__(256, 2)
__global__ void k_attn(const bf16* __restrict__ down, float* __restrict__ Opart,
                       float* __restrict__ Mpart, float* __restrict__ Lpart) {
    __shared__ bf16 Qs[64][136];
    __shared__ bf16 Ks[64][136];      // token tile row-major [t][d]
    __shared__ bf16 Vt[128][72];      // transposed [d][t], VT_COL swizzled
    __shared__ bf16 Ps[4][16][72];    // per-wave P tile [q][t]
    const int tid = threadIdx.x;
    const int lane = tid & 63, w = tid >> 6;
    const int li = lane & 15, lg = lane >> 4;
    // bijective XCD swizzle (512 % 8 == 0): XCD x gets 64 contiguous wgs
    const int bid = blockIdx.x;
    const int wg = (bid & 7) * 64 + (bid >> 3);
    const int b  = wg >> 4;
    const int qt = (wg >> 2) & 3;
    const int th = wg & 3;
    const size_t base = (size_t)b * N_ * D_;
    const int tbase = P_ + th * 512;

    // stage Q (rows qt*64 .. +63)
#pragma unroll
    for (int it = 0; it < 4; it++) {
        int ch = tid + it * 256;            // 1024 chunks of 8
        int r = ch >> 4, c8 = (ch & 15) * 8;
        *(u32x4*)&Qs[r][c8] = *(const u32x4*)(down + base + (size_t)(qt * 64 + r) * D_ + c8);
    }
    __syncthreads();
    bf16x8 qf[4];
#pragma unroll
    for (int kk = 0; kk < 4; kk++)
        qf[kk] = *(const bf16x8*)&Qs[w * 16 + li][kk * 32 + lg * 8];

    float m_run[4], l_run[4];
    f32x4 acc[8];
    const f32x4 zero = {0.f, 0.f, 0.f, 0.f};
#pragma unroll
    for (int r = 0; r < 4; r++) { m_run[r] = -3.0e38f; l_run[r] = 0.f; }
#pragma unroll
    for (int fn = 0; fn < 8; fn++) acc[fn] = zero;

    for (int tt = 0; tt < 8; tt++) {
        __syncthreads();
        // stage token tile: row-major K copy + swizzled transposed V copy
#pragma unroll
        for (int it = 0; it < 4; it++) {
            int ch = tid + it * 256;
            int r = ch >> 4, c8 = (ch & 15) * 8;
            u32x4 v = *(const u32x4*)(down + base + (size_t)(tbase + tt * 64 + r) * D_ + c8);
            *(u32x4*)&Ks[r][c8] = v;
            bf16 tmp[8];
            *(u32x4*)tmp = v;
#pragma unroll
            for (int j = 0; j < 8; j++) Vt[c8 + j][VT_COL(c8 + j, r)] = tmp[j];
        }
        __syncthreads();
        // S = Q K^T * scale   (wave: 16 q x 64 t)
        f32x4 s[4];
#pragma unroll
        for (int fn = 0; fn < 4; fn++) {
            s[fn] = zero;
#pragma unroll
            for (int kk = 0; kk < 4; kk++) {
                bf16x8 kf = *(const bf16x8*)&Ks[fn * 16 + li][kk * 32 + lg * 8];
                s[fn] = __builtin_amdgcn_mfma_f32_16x16x32_bf16(qf[kk], kf, s[fn], 0, 0, 0);
            }
            s[fn] *= SCALE_;
        }
        // online softmax (rows shared by 16-lane group; reduce over li)
#pragma unroll
        for (int r = 0; r < 4; r++) {
            float tmax = fmaxf(fmaxf(s[0][r], s[1][r]), fmaxf(s[2][r], s[3][r]));
#pragma unroll
            for (int off = 1; off < 16; off <<= 1)
                tmax = fmaxf(tmax, __shfl_xor(tmax, off, 64));
            float mnew = fmaxf(m_run[r], tmax);
            float corr = __expf(m_run[r] - mnew);
            m_run[r] = mnew;
            float psum = 0.f;
#pragma unroll
            for (int fn = 0; fn < 4; fn++) {
                float p = __expf(s[fn][r] - mnew);
                psum += p;
                Ps[w][lg * 4 + r][fn * 16 + li] = (bf16)p;
            }
#pragma unroll
            for (int off = 1; off < 16; off <<= 1)
                psum += __shfl_xor(psum, off, 64);
            l_run[r] = l_run[r] * corr + psum;
#pragma unroll
            for (int fn = 0; fn < 8; fn++) acc[fn][r] *= corr;
        }
        // O += P V   (P: 16x64 per wave, V: 64x128)
#pragma unroll
        for (int kk = 0; kk < 2; kk++) {
            bf16x8 pf = *(const bf16x8*)&Ps[w][li][kk * 32 + lg * 8];
#pragma unroll
            for (int fn = 0; fn < 8; fn++) {
                int d = fn * 16 + li;
                bf16x8 vf = *(const bf16x8*)&Vt[d][VT_COL(d, kk * 32 + lg * 8)];
                acc[fn] = __builtin_amdgcn_mfma_f32_16x16x32_bf16(pf, vf, acc[fn], 0, 0, 0);
            }
        }
    }
    // epilogue: store unnormalized partials + (m, l) for all 64 q rows
#pragma unroll
    for (int r = 0; r < 4; r++) {
        int q = qt * 64 + w * 16 + lg * 4 + r;
        size_t ro = ((size_t)(b * 4 + th) * 256 + q) * 128;
#pragma unroll
        for (int fn = 0; fn < 8; fn++)
            Opart[ro + fn * 16 + li] = acc[fn][r];
        if (li == 0) {
            Mpart[(b * 4 + th) * 256 + q] = m_run[r];
            Lpart[(b * 4 + th) * 256 + q] = l_run[r];
        }
    }
}

// ---------------------------------------------------------------------------
// Kernel B2: combine the four token-quarter partials into pout (bf16).
// 819200 elems / 4 per thread = 204800 threads = 800 blocks x 256.
// ---------------------------------------------------------------------------
__global__ void k_comb(const float* __restrict__ Opart, const float* __restrict__ Mpart,
                       const float* __restrict__ Lpart, bf16* __restrict__ pout) {
    int gid = blockIdx.x * 256 + threadIdx.x;
    if (gid >= (B_ * P_ * D_) / 4) return;
    int e = gid * 4;
    int row = e >> 7;                 // 0..6399  (b*200+q)
    int col = e & 127;
    int b = row / P_;
    int q = row - b * P_;
    float mm[4], ll[4];
    float m = -3.0e38f;
#pragma unroll
    for (int t = 0; t < 4; t++) {
        mm[t] = Mpart[(b * 4 + t) * 256 + q];
        ll[t] = Lpart[(b * 4 + t) * 256 + q];
        m = fmaxf(m, mm[t]);
    }
    float a[4], lsum = 0.f;
#pragma unroll
    for (int t = 0; t < 4; t++) { a[t] = __expf(mm[t] - m); lsum += ll[t] * a[t]; }
    float inv = 1.0f / lsum;
    f32x4 o = {0.f, 0.f, 0.f, 0.f};
#pragma unroll
    for (int t = 0; t < 4; t++) {
        f32x4 ot = *(const f32x4*)&Opart[((size_t)(b * 4 + t) * 256 + q) * 128 + col];
#pragma unroll
        for (int j = 0; j < 4; j++) o[j] += ot[j] * a[t];
    }
    bf16x4 ob;
#pragma unroll
    for (int j = 0; j < 4; j++) ob[j] = (bf16)(o[j] * inv);
    *(bf16x4*)&pout[(size_t)row * 128 + col] = ob;
}

// ---------------------------------------------------------------------------
// Kernel C: out = gate * (combined @ W_up + b_up).  K=128 single shot.
// DIRECT-FRAGMENT GEMM: no LDS, no barriers. All loads issue up front
// (single K block -> no dependent per-iteration chain).
// 128x128 tile, 4 waves (2x2). XCD-aware block swizzle (4496 % 8 == 0).
// ---------------------------------------------------------------------------
__launch_bounds__(256, 3)
__global__ void k_up(const bf16* __restrict__ down, const bf16* __restrict__ pout,
                     const bf16* __restrict__ WtU, const float* __restrict__ bu,
                     const float* __restrict__ gate, float* __restrict__ out) {
    const int tid = threadIdx.x;
    const int lane = tid & 63, wid = tid >> 6;
    const int wm = wid >> 1, wn = wid & 1;
    const int li = lane & 15, lg = lane >> 4;
    // bijective XCD swizzle: XCD x gets contiguous wg range [562x, 562x+562)
    int bid = blockIdx.x;
    int wg = (bid & 7) * 562 + (bid >> 3);
    const int mt = wg >> 3, nt = wg & 7;
    const int m0 = mt * 128, n0 = nt * 128;

    // per-lane A row pointers (combined matrix), one per fm fragment
    const bf16* rp[4];
#pragma unroll
    for (int f = 0; f < 4; f++) {
        int row = m0 + wm * 64 + f * 16 + li;
        int bb = row / N_;
        int n = row - bb * N_;
        rp[f] = (n < P_) ? (pout + (size_t)(bb * P_ + n) * D_ + lg * 8)
                         : (down + (size_t)row * D_ + lg * 8);
    }
    const bf16* Bp = WtU + (size_t)(n0 + wn * 64 + li) * D_ + lg * 8;

    f32x4 acc[4][4];
    const f32x4 zero = {0.f, 0.f, 0.f, 0.f};
#pragma unroll
    for (int i = 0; i < 4; i++)
#pragma unroll
        for (int j = 0; j < 4; j++) acc[i][j] = zero;

#pragma unroll
    for (int kk = 0; kk < 4; kk++) {
        bf16x8 af[4], bf_[4];
#pragma unroll
        for (int f = 0; f < 4; f++) {
            af[f]  = *(const bf16x8*)(rp[f] + kk * 32);
            bf_[f] = *(const bf16x8*)(Bp + (size_t)(f * 16) * D_ + kk * 32);
        }
#pragma unroll
        for (int fm = 0; fm < 4; fm++)
#pragma unroll
            for (int fn = 0; fn < 4; fn++)
                acc[fm][fn] = __builtin_amdgcn_mfma_f32_16x16x32_bf16(
                    af[fm], bf_[fn], acc[fm][fn], 0, 0, 0);
    }

    float g = gate[0];
#pragma unroll
    for (int fn = 0; fn < 4; fn++) {
        int c = n0 + wn * 64 + fn * 16 + li;
        float bias = bu[c];
#pragma unroll
        for (int fm = 0; fm < 4; fm++) {
            int rb = m0 + wm * 64 + fm * 16 + lg * 4;
#pragma unroll
            for (int r = 0; r < 4; r++)
                out[(size_t)(rb + r) * C_ + c] = g * (acc[fm][fn][r] + bias);
        }
    }
}

// ---------------------------------------------------------------------------
extern "C" void kernel_launch(void* const* d_in, const int* in_sizes, int n_in,
                              void* d_out, int out_size, void* d_ws, size_t ws_size,
                              hipStream_t stream) {
    const float* x    = (const float*)d_in[0];
    const float* Wd   = (const float*)d_in[1];
    const float* bd   = (const float*)d_in[2];
    const float* Wu   = (const float*)d_in[3];
    const float* bu   = (const float*)d_in[4];
    const float* gate = (const float*)d_in[5];
    float* out = (float*)d_out;

    char* w = (char*)d_ws;
    bf16*  down  = (bf16*)w;                          // 71936*128*2 = 18,415,616 B
    bf16*  pout  = (bf16*)(w + 18415616);             // 32*200*128*2 = 1,638,400 B
    bf16*  WtD   = (bf16*)(w + 20054016);             // 262,144 B
    bf16*  WtU   = (bf16*)(w + 20316160);             // 262,144 B
    float* Opart = (float*)(w + 20578304);            // 32*4*256*128*4 = 16,777,216 B
    float* Mpart = (float*)(w + 37355520);            // 131,072 B
    float* Lpart = (float*)(w + 37486592);            // 131,072 B  (total 37.6 MB)

    k_prep<<<512, 256, 0, stream>>>(Wd, Wu, WtD, WtU);
    k_down<<<M_ / 128, 256, 0, stream>>>(x, WtD, bd, down);            // 562 blocks
    k_attn<<<512, 256, 0, stream>>>(down, Opart, Mpart, Lpart);        // 512 blocks
    k_comb<<<800, 256, 0, stream>>>(Opart, Mpart, Lpart, pout);        // 800 blocks
    k_up<<<(M_ / 128) * 8, 256, 0, stream>>>(down, pout, WtU, bu, gate, out); // 4496
}

// Round 10
// 236.084 us; speedup vs baseline: 1.5718x; 1.1268x over previous
//
#include <hip/hip_runtime.h>
#include <hip/hip_bf16.h>
#include <math.h>

// Problem constants
#define B_   32
#define N_   2248
#define C_   1024
#define D_   128
#define P_   200
#define T_   2048            // N_ - P_
#define M_   (B_ * N_)       // 71936 rows total
#define SCALE_ 0.08838834764831845f  // D^-0.5

typedef __bf16 bf16;
typedef __bf16 bf16x8 __attribute__((ext_vector_type(8)));
typedef __bf16 bf16x4 __attribute__((ext_vector_type(4)));
typedef float  f32x4  __attribute__((ext_vector_type(4)));
typedef unsigned int u32x4 __attribute__((ext_vector_type(4)));

// V-transpose LDS column swizzle (attn)
#define VT_COL(dd, t) ((((((t) >> 3) ^ (((dd) >> 3) & 7)) << 3)) | ((t) & 7))

// direct-to-LDS 16B async copy (no VGPR round-trip; nothing for the
// scheduler to sink, no register cost)
__device__ __forceinline__ void gl_lds16(const void* g, void* l) {
    __builtin_amdgcn_global_load_lds(
        (const __attribute__((address_space(1))) unsigned int*)g,
        (__attribute__((address_space(3))) unsigned int*)l,
        16, 0, 0);
}

// ---------------------------------------------------------------------------
// Kernel 0: one-time weight transpose + bf16 convert.
// WtD[d][k] = W_down[k][d] (d<128, k<1024);  WtU[c][d] = W_up[d][c]
// ---------------------------------------------------------------------------
__global__ void k_prep(const float* __restrict__ Wd, const float* __restrict__ Wu,
                       bf16* __restrict__ WtD, bf16* __restrict__ WtU) {
    int i = blockIdx.x * 256 + threadIdx.x;
    if (i >= 131072) return;
    int d = i >> 10, k = i & 1023;
    WtD[i] = (bf16)Wd[k * 128 + d];
    int c = i >> 7, e = i & 127;
    WtU[i] = (bf16)Wu[e * 1024 + c];
}

// ---------------------------------------------------------------------------
// Kernel A: down = gelu(x @ W_down + b_down), bf16 out.
// T3+T4 pipeline: gl_lds ring-3, counted vmcnt, RAW s_barrier (never vmcnt(0)
// in the loop). Both A and B staged by gl_lds -> the K-loop issues NO
// vgpr-returning VMEM, so no compiler waitcnt can drain the ring.
//   iter t: asm vmcnt(4)  [tile t landed; t+1,t+2 stay in flight]
//           s_barrier     [all waves' tile-t portions landed]
//           issue tile t+2 into slot (t-1)%3  [safe: all waves past t-1 reads]
//           compute tile t (ds_read + cvt + 8 MFMA)
// Tile 64x128, BK=32, 32 steps. A: [64][32]f32 8KB; B: WtD[128][32]bf16 8KB.
// XOR swizzle both-sides (rule #21): pre-swizzled global src, swizzled read.
// LDS 48KB -> 3 blocks/CU (12 waves). grid = 1124.
// ---------------------------------------------------------------------------
__launch_bounds__(256, 3)
__global__ void k_down(const float* __restrict__ x, const bf16* __restrict__ WtD,
                       const float* __restrict__ bd, bf16* __restrict__ down) {
    __shared__ __align__(16) char ring[3][16384];   // slot: A @0 (8KB), B @8192 (8KB)
    const int tid = threadIdx.x;
    const int lane = tid & 63, w = tid >> 6;
    const int wm = w >> 1, wn = w & 1;
    const int li = lane & 15, lg = lane >> 4;
    const int m0 = blockIdx.x * 64;

    // staging descriptors. Wave w owns chunks {2w, 2w+1} of A and of B.
    // A chunk c: rows c*8 + (lane>>3), 128B/row; dest pos (lane&7) holds
    // logical 16B-chunk (lane&7)^(row&7)  -> source col pre-swizzled.
    const int cA0 = w * 2, cA1 = w * 2 + 1;
    const int ar0 = cA0 * 8 + (lane >> 3);
    const int ar1 = cA1 * 8 + (lane >> 3);
    const float* asrc0 = x + (size_t)(m0 + ar0) * C_ + ((((lane & 7) ^ (ar0 & 7)) * 16) >> 2);
    const float* asrc1 = x + (size_t)(m0 + ar1) * C_ + ((((lane & 7) ^ (ar1 & 7)) * 16) >> 2);
    // B chunk c: rows c*16 + (lane>>2), 64B/row; dest pos (lane&3) holds
    // logical chunk (lane&3)^(row&3).
    const int br0 = cA0 * 16 + (lane >> 2);
    const int br1 = cA1 * 16 + (lane >> 2);
    const bf16* bsrc0 = WtD + (size_t)br0 * C_ + (((lane & 3) ^ (br0 & 3)) * 8);
    const bf16* bsrc1 = WtD + (size_t)br1 * C_ + (((lane & 3) ^ (br1 & 3)) * 8);

#define STAGE_(t_, s_) do {                                              \
        gl_lds16(asrc0 + (t_) * 32, ring[s_] + cA0 * 1024);              \
        gl_lds16(asrc1 + (t_) * 32, ring[s_] + cA1 * 1024);              \
        gl_lds16(bsrc0 + (t_) * 32, ring[s_] + 8192 + cA0 * 1024);       \
        gl_lds16(bsrc1 + (t_) * 32, ring[s_] + 8192 + cA1 * 1024);       \
    } while (0)

    f32x4 acc[2][4];
    const f32x4 zero = {0.f, 0.f, 0.f, 0.f};
#pragma unroll
    for (int i = 0; i < 2; i++)
#pragma unroll
        for (int j = 0; j < 4; j++) acc[i][j] = zero;

    // prologue: tiles 0 and 1 in flight
    STAGE_(0, 0);
    STAGE_(1, 1);

    for (int t = 0; t < 32; t++) {
        // wait for OWN tile-t loads (4 newest = tiles t+1,t+2 stay in flight)
        if (t < 31) { asm volatile("s_waitcnt vmcnt(4)" ::: "memory"); }
        else        { asm volatile("s_waitcnt vmcnt(0)" ::: "memory"); }
        __builtin_amdgcn_sched_barrier(0);
        __builtin_amdgcn_s_barrier();          // raw: no vmcnt(0) drain
        __builtin_amdgcn_sched_barrier(0);
        if (t + 2 < 32) {
            int s = (t + 2) % 3;               // == (t-1)%3: consumed last iter
            STAGE_(t + 2, s);
        }
        const char* sa = ring[t % 3];
        const char* sb = sa + 8192;
        // A fragments: row wm*32+f*16+li, k = lg*8..+7 (f32, cvt to bf16)
        bf16x8 af[2];
#pragma unroll
        for (int f = 0; f < 2; f++) {
            int row = wm * 32 + f * 16 + li;
            const char* rb = sa + row * 128;
            int p0 = (2 * lg) ^ (row & 7), p1 = (2 * lg + 1) ^ (row & 7);
            f32x4 a0 = *(const f32x4*)(rb + p0 * 16);
            f32x4 a1 = *(const f32x4*)(rb + p1 * 16);
            bf16x8 o;
            o[0] = (bf16)a0[0]; o[1] = (bf16)a0[1]; o[2] = (bf16)a0[2]; o[3] = (bf16)a0[3];
            o[4] = (bf16)a1[0]; o[5] = (bf16)a1[1]; o[6] = (bf16)a1[2]; o[7] = (bf16)a1[3];
            af[f] = o;
        }
        // B fragments: row wn*64+f*16+li, k = lg*8..+7 (bf16 direct)
        bf16x8 bfr[4];
#pragma unroll
        for (int f = 0; f < 4; f++) {
            int row = wn * 64 + f * 16 + li;
            bfr[f] = *(const bf16x8*)(sb + row * 64 + ((lg ^ (row & 3)) * 16));
        }
#pragma unroll
        for (int fm = 0; fm < 2; fm++)
#pragma unroll
            for (int fn = 0; fn < 4; fn++)
                acc[fm][fn] = __builtin_amdgcn_mfma_f32_16x16x32_bf16(
                    af[fm], bfr[fn], acc[fm][fn], 0, 0, 0);
    }
#undef STAGE_

    // epilogue: bias + exact gelu, store bf16
#pragma unroll
    for (int fn = 0; fn < 4; fn++) {
        int col = wn * 64 + fn * 16 + li;
        float bias = bd[col];
#pragma unroll
        for (int fm = 0; fm < 2; fm++) {
            int rb = m0 + wm * 32 + fm * 16 + lg * 4;
#pragma unroll
            for (int r = 0; r < 4; r++) {
                float v = acc[fm][fn][r] + bias;
                float g = 0.5f * v * (1.0f + erff(v * 0.70710678118654752f));
                down[(size_t)(rb + r) * D_ + col] = (bf16)g;
            }
        }
    }
}

// ---------------------------------------------------------------------------
// Kernel B: flash attention, SPLIT over tokens (4 quarters of 512).
// grid = 32 b x 4 qtile x 4 thalf = 512 blocks (2/CU), XCD-swizzled.
// ---------------------------------------------------------------------------
__launch_bounds__(256, 2)
__global__ void k_attn(const bf16* __restrict__ down, float* __restrict__ Opart,
                       float* __restrict__ Mpart, float* __restrict__ Lpart) {
    __shared__ bf16 Qs[64][136];
    __shared__ bf16 Ks[64][136];
    __shared__ bf16 Vt[128][72];
    __shared__ bf16 Ps[4][16][72];
    const int tid = threadIdx.x;
    const int lane = tid & 63, w = tid >> 6;
    const int li = lane & 15, lg = lane >> 4;
    const int bid = blockIdx.x;
    const int wg = (bid & 7) * 64 + (bid >> 3);
    const int b  = wg >> 4;
    const int qt = (wg >> 2) & 3;
    const int th = wg & 3;
    const size_t base = (size_t)b * N_ * D_;
    const int tbase = P_ + th * 512;

#pragma unroll
    for (int it = 0; it < 4; it++) {
        int ch = tid + it * 256;
        int r = ch >> 4, c8 = (ch & 15) * 8;
        *(u32x4*)&Qs[r][c8] = *(const u32x4*)(down + base + (size_t)(qt * 64 + r) * D_ + c8);
    }
    __syncthreads();
    bf16x8 qf[4];
#pragma unroll
    for (int kk = 0; kk < 4; kk++)
        qf[kk] = *(const bf16x8*)&Qs[w * 16 + li][kk * 32 + lg * 8];

    float m_run[4], l_run[4];
    f32x4 acc[8];
    const f32x4 zero = {0.f, 0.f, 0.f, 0.f};
#pragma unroll
    for (int r = 0; r < 4; r++) { m_run[r] = -3.0e38f; l_run[r] = 0.f; }
#pragma unroll
    for (int fn = 0; fn < 8; fn++) acc[fn] = zero;

    for (int tt = 0; tt < 8; tt++) {
        __syncthreads();
#pragma unroll
        for (int it = 0; it < 4; it++) {
            int ch = tid + it * 256;
            int r = ch >> 4, c8 = (ch & 15) * 8;
            u32x4 v = *(const u32x4*)(down + base + (size_t)(tbase + tt * 64 + r) * D_ + c8);
            *(u32x4*)&Ks[r][c8] = v;
            bf16 tmp[8];
            *(u32x4*)tmp = v;
#pragma unroll
            for (int j = 0; j < 8; j++) Vt[c8 + j][VT_COL(c8 + j, r)] = tmp[j];
        }
        __syncthreads();
        f32x4 s[4];
#pragma unroll
        for (int fn = 0; fn < 4; fn++) {
            s[fn] = zero;
#pragma unroll
            for (int kk = 0; kk < 4; kk++) {
                bf16x8 kf = *(const bf16x8*)&Ks[fn * 16 + li][kk * 32 + lg * 8];
                s[fn] = __builtin_amdgcn_mfma_f32_16x16x32_bf16(qf[kk], kf, s[fn], 0, 0, 0);
            }
            s[fn] *= SCALE_;
        }
#pragma unroll
        for (int r = 0; r < 4; r++) {
            float tmax = fmaxf(fmaxf(s[0][r], s[1][r]), fmaxf(s[2][r], s[3][r]));
#pragma unroll
            for (int off = 1; off < 16; off <<= 1)
                tmax = fmaxf(tmax, __shfl_xor(tmax, off, 64));
            float mnew = fmaxf(m_run[r], tmax);
            float corr = __expf(m_run[r] - mnew);
            m_run[r] = mnew;
            float psum = 0.f;
#pragma unroll
            for (int fn = 0; fn < 4; fn++) {
                float p = __expf(s[fn][r] - mnew);
                psum += p;
                Ps[w][lg * 4 + r][fn * 16 + li] = (bf16)p;
            }
#pragma unroll
            for (int off = 1; off < 16; off <<= 1)
                psum += __shfl_xor(psum, off, 64);
            l_run[r] = l_run[r] * corr + psum;
#pragma unroll
            for (int fn = 0; fn < 8; fn++) acc[fn][r] *= corr;
        }
#pragma unroll
        for (int kk = 0; kk < 2; kk++) {
            bf16x8 pf = *(const bf16x8*)&Ps[w][li][kk * 32 + lg * 8];
#pragma unroll
            for (int fn = 0; fn < 8; fn++) {
                int d = fn * 16 + li;
                bf16x8 vf = *(const bf16x8*)&Vt[d][VT_COL(d, kk * 32 + lg * 8)];
                acc[fn] = __builtin_amdgcn_mfma_f32_16x16x32_bf16(pf, vf, acc[fn], 0, 0, 0);
            }
        }
    }
#pragma unroll
    for (int r = 0; r < 4; r++) {
        int q = qt * 64 + w * 16 + lg * 4 + r;
        size_t ro = ((size_t)(b * 4 + th) * 256 + q) * 128;
#pragma unroll
        for (int fn = 0; fn < 8; fn++)
            Opart[ro + fn * 16 + li] = acc[fn][r];
        if (li == 0) {
            Mpart[(b * 4 + th) * 256 + q] = m_run[r];
            Lpart[(b * 4 + th) * 256 + q] = l_run[r];
        }
    }
}

// ---------------------------------------------------------------------------
// Kernel B2: combine the four token-quarter partials into pout (bf16).
// ---------------------------------------------------------------------------
__global__ void k_comb(const float* __restrict__ Opart, const float* __restrict__ Mpart,
                       const float* __restrict__ Lpart, bf16* __restrict__ pout) {
    int gid = blockIdx.x * 256 + threadIdx.x;
    if (gid >= (B_ * P_ * D_) / 4) return;
    int e = gid * 4;
    int row = e >> 7;
    int col = e & 127;
    int b = row / P_;
    int q = row - b * P_;
    float mm[4], ll[4];
    float m = -3.0e38f;
#pragma unroll
    for (int t = 0; t < 4; t++) {
        mm[t] = Mpart[(b * 4 + t) * 256 + q];
        ll[t] = Lpart[(b * 4 + t) * 256 + q];
        m = fmaxf(m, mm[t]);
    }
    float a[4], lsum = 0.f;
#pragma unroll
    for (int t = 0; t < 4; t++) { a[t] = __expf(mm[t] - m); lsum += ll[t] * a[t]; }
    float inv = 1.0f / lsum;
    f32x4 o = {0.f, 0.f, 0.f, 0.f};
#pragma unroll
    for (int t = 0; t < 4; t++) {
        f32x4 ot = *(const f32x4*)&Opart[((size_t)(b * 4 + t) * 256 + q) * 128 + col];
#pragma unroll
        for (int j = 0; j < 4; j++) o[j] += ot[j] * a[t];
    }
    bf16x4 ob;
#pragma unroll
    for (int j = 0; j < 4; j++) ob[j] = (bf16)(o[j] * inv);
    *(bf16x4*)&pout[(size_t)row * 128 + col] = ob;
}

// ---------------------------------------------------------------------------
// Kernel C: out = gate * (combined @ W_up + b_up).  K=128 single shot.
// DIRECT-FRAGMENT GEMM (proven in r3's 255.7 total).
// ---------------------------------------------------------------------------
__launch_bounds__(256, 3)
__global__ void k_up(const bf16* __restrict__ down, const bf16* __restrict__ pout,
                     const bf16* __restrict__ WtU, const float* __restrict__ bu,
                     const float* __restrict__ gate, float* __restrict__ out) {
    const int tid = threadIdx.x;
    const int lane = tid & 63, wid = tid >> 6;
    const int wm = wid >> 1, wn = wid & 1;
    const int li = lane & 15, lg = lane >> 4;
    int bid = blockIdx.x;
    int wg = (bid & 7) * 562 + (bid >> 3);
    const int mt = wg >> 3, nt = wg & 7;
    const int m0 = mt * 128, n0 = nt * 128;

    const bf16* rp[4];
#pragma unroll
    for (int f = 0; f < 4; f++) {
        int row = m0 + wm * 64 + f * 16 + li;
        int bb = row / N_;
        int n = row - bb * N_;
        rp[f] = (n < P_) ? (pout + (size_t)(bb * P_ + n) * D_ + lg * 8)
                         : (down + (size_t)row * D_ + lg * 8);
    }
    const bf16* Bp = WtU + (size_t)(n0 + wn * 64 + li) * D_ + lg * 8;

    f32x4 acc[4][4];
    const f32x4 zero = {0.f, 0.f, 0.f, 0.f};
#pragma unroll
    for (int i = 0; i < 4; i++)
#pragma unroll
        for (int j = 0; j < 4; j++) acc[i][j] = zero;

#pragma unroll
    for (int kk = 0; kk < 4; kk++) {
        bf16x8 af[4], bf_[4];
#pragma unroll
        for (int f = 0; f < 4; f++) {
            af[f]  = *(const bf16x8*)(rp[f] + kk * 32);
            bf_[f] = *(const bf16x8*)(Bp + (size_t)(f * 16) * D_ + kk * 32);
        }
#pragma unroll
        for (int fm = 0; fm < 4; fm++)
#pragma unroll
            for (int fn = 0; fn < 4; fn++)
                acc[fm][fn] = __builtin_amdgcn_mfma_f32_16x16x32_bf16(
                    af[fm], bf_[fn], acc[fm][fn], 0, 0, 0);
    }

    float g = gate[0];
#pragma unroll
    for (int fn = 0; fn < 4; fn++) {
        int c = n0 + wn * 64 + fn * 16 + li;
        float bias = bu[c];
#pragma unroll
        for (int fm = 0; fm < 4; fm++) {
            int rb = m0 + wm * 64 + fm * 16 + lg * 4;
#pragma unroll
            for (int r = 0; r < 4; r++)
                out[(size_t)(rb + r) * C_ + c] = g * (acc[fm][fn][r] + bias);
        }
    }
}

// ---------------------------------------------------------------------------
extern "C" void kernel_launch(void* const* d_in, const int* in_sizes, int n_in,
                              void* d_out, int out_size, void* d_ws, size_t ws_size,
                              hipStream_t stream) {
    const float* x    = (const float*)d_in[0];
    const float* Wd   = (const float*)d_in[1];
    const float* bd   = (const float*)d_in[2];
    const float* Wu   = (const float*)d_in[3];
    const float* bu   = (const float*)d_in[4];
    const float* gate = (const float*)d_in[5];
    float* out = (float*)d_out;

    char* w = (char*)d_ws;
    bf16*  down  = (bf16*)w;                          // 18,415,616 B
    bf16*  pout  = (bf16*)(w + 18415616);             // 1,638,400 B
    bf16*  WtD   = (bf16*)(w + 20054016);             // 262,144 B
    bf16*  WtU   = (bf16*)(w + 20316160);             // 262,144 B
    float* Opart = (float*)(w + 20578304);            // 16,777,216 B
    float* Mpart = (float*)(w + 37355520);            // 131,072 B
    float* Lpart = (float*)(w + 37486592);            // 131,072 B

    k_prep<<<512, 256, 0, stream>>>(Wd, Wu, WtD, WtU);
    k_down<<<M_ / 64, 256, 0, stream>>>(x, WtD, bd, down);             // 1124 blocks
    k_attn<<<512, 256, 0, stream>>>(down, Opart, Mpart, Lpart);        // 512 blocks
    k_comb<<<800, 256, 0, stream>>>(Opart, Mpart, Lpart, pout);        // 800 blocks
    k_up<<<(M_ / 128) * 8, 256, 0, stream>>>(down, pout, WtU, bu, gate, out); // 4496
}